// Round 1
// baseline (361.901 us; speedup 1.0000x reference)
//
#include <hip/hip_runtime.h>
#include <hip/hip_bf16.h>

#define T_TOK 2048
#define DIM   1024
#define NEXP  16
#define HID   2048

typedef __attribute__((ext_vector_type(8))) short short8;
typedef __attribute__((ext_vector_type(4))) float f32x4;

__device__ __forceinline__ unsigned short f2bf(float f) {
  __hip_bfloat16 h = __float2bfloat16(f);
  union { __hip_bfloat16 b; unsigned short u; } cv; cv.b = h; return cv.u;
}

// ---------------- init: zero counters ----------------
__global__ void init_k(int* cnt, int* fill) {
  int i = threadIdx.x;
  if (i < NEXP) { cnt[i] = 0; fill[i] = 0; }
}

// ---------------- router: fp32, one wave per token ----------------
__global__ __launch_bounds__(256) void router_k(const float* __restrict__ x,
    const float* __restrict__ Wr, const float* __restrict__ br,
    int* __restrict__ re, float* __restrict__ rwv, int* __restrict__ cnt)
{
  const int wid = threadIdx.x >> 6, lane = threadIdx.x & 63;
  const int t = blockIdx.x * 4 + wid;
  const float* xr = x + (size_t)t * DIM;
  float acc[NEXP];
#pragma unroll
  for (int e = 0; e < NEXP; e++) acc[e] = 0.f;
  for (int i = 0; i < DIM / 64; i++) {
    const int d = lane + 64 * i;
    const float xv = xr[d];
    const float4* w4 = reinterpret_cast<const float4*>(Wr + (size_t)d * NEXP);
#pragma unroll
    for (int q = 0; q < 4; q++) {
      float4 w = w4[q];
      acc[4*q+0] += xv * w.x; acc[4*q+1] += xv * w.y;
      acc[4*q+2] += xv * w.z; acc[4*q+3] += xv * w.w;
    }
  }
#pragma unroll
  for (int e = 0; e < NEXP; e++) {
    float v = acc[e];
    v += __shfl_xor(v, 32); v += __shfl_xor(v, 16); v += __shfl_xor(v, 8);
    v += __shfl_xor(v, 4);  v += __shfl_xor(v, 2);  v += __shfl_xor(v, 1);
    acc[e] = v;
  }
  if (lane == 0) {
    float lg[NEXP];
#pragma unroll
    for (int e = 0; e < NEXP; e++) lg[e] = acc[e] + br[e];  // TEMP = 1.0
    int e0 = 0; float b0 = lg[0];
    for (int e = 1; e < NEXP; e++) if (lg[e] > b0) { b0 = lg[e]; e0 = e; }
    int e1 = (e0 == 0) ? 1 : 0; float b1v = lg[e1];
    for (int e = 0; e < NEXP; e++) if (e != e0 && lg[e] > b1v) { b1v = lg[e]; e1 = e; }
    float p1 = expf(b1v - b0);               // p0 = 1
    float inv = 1.0f / (1.0f + p1);
    re[2*t] = e0; re[2*t+1] = e1;
    rwv[2*t] = inv; rwv[2*t+1] = p1 * inv;
    atomicAdd(&cnt[e0], 1); atomicAdd(&cnt[e1], 1);
  }
}

// ---------------- scan: 16-entry exclusive prefix ----------------
__global__ void scan_k(const int* cnt, int* basev) {
  if (threadIdx.x == 0) {
    int s = 0;
    for (int e = 0; e < NEXP; e++) { basev[e] = s; s += cnt[e]; }
  }
}

// ---------------- scatter: build per-expert row lists ----------------
__global__ __launch_bounds__(256) void scatter_k(const int* __restrict__ re,
    const float* __restrict__ rwv, const int* __restrict__ basev, int* fill,
    int* __restrict__ rows_token, float* __restrict__ rows_w, int* __restrict__ slot_of)
{
  int t = blockIdx.x * 256 + threadIdx.x;
  if (t >= T_TOK) return;
  for (int k = 0; k < 2; k++) {
    int e = re[2*t+k];
    int pos = atomicAdd(&fill[e], 1);
    int row = basev[e] + pos;
    rows_token[row] = t;
    rows_w[row] = rwv[2*t+k];
    slot_of[2*t+k] = row;
  }
}

// ---------------- grouped expert GEMM (fc1 / fc2) ----------------
// fc1: A = gathered x (fp32->bf16), B = W1[e] (K=DIM, N=HID), out = GELU -> hbuf (bf16)
// fc2: A = hbuf (bf16),             B = W2[e] (K=HID, N=DIM), out = w*(acc+b2) -> obuf (f32)
template<bool FC1>
__global__ __launch_bounds__(512) void expert_gemm_k(
    const float* __restrict__ x, const unsigned short* __restrict__ hin,
    const float* __restrict__ Wg, const float* __restrict__ bg,
    const int* __restrict__ cnt, const int* __restrict__ basev,
    const int* __restrict__ rows_token, const float* __restrict__ rows_w,
    unsigned short* __restrict__ hout, float* __restrict__ obuf)
{
  constexpr int KD = FC1 ? DIM : HID;
  constexpr int ND = FC1 ? HID : DIM;
  constexpr int BM = 256, BN = 128, BK = 32, LDP = 36;
  const int e = blockIdx.z, mt = blockIdx.y, nt = blockIdx.x;
  const int Ne = cnt[e];
  if (mt * BM >= Ne) return;
  const int base = basev[e];
  __shared__ unsigned short As[BM][LDP];
  __shared__ unsigned short Bs[BN][LDP];
  const int tid = threadIdx.x;
  const float* W = Wg + (size_t)e * KD * ND + (size_t)nt * BN;

  // A staging assignment: 256 rows x 8 k-quads = 2048 slots / 512 thr = 4 each
  int arow[4], akq[4];
  const float* aptrf[4];
  const unsigned short* aptrh[4];
#pragma unroll
  for (int i = 0; i < 4; i++) {
    int flat = tid + 512 * i;
    int row = flat >> 3, kq = flat & 7;
    arow[i] = row; akq[i] = kq;
    int m = mt * BM + row; if (m > Ne - 1) m = Ne - 1;   // clamp (masked at epilogue)
    if constexpr (FC1) {
      int tok = rows_token[base + m];
      aptrf[i] = x + (size_t)tok * DIM + kq * 4;
    } else {
      aptrh[i] = hin + (size_t)(base + m) * HID + kq * 4;
    }
  }
  // B staging assignment: 128 n x 8 k-quads = 1024 slots / 512 thr = 2 each
  int bn_[2], bkq_[2];
#pragma unroll
  for (int i = 0; i < 2; i++) {
    int flat = tid + 512 * i;
    bn_[i] = flat & (BN - 1);
    bkq_[i] = flat >> 7;
  }

  const int wid = tid >> 6, lane = tid & 63;
  const int wr = wid >> 1, wc = wid & 1;         // 4 m-bands x 2 n-bands of 64
  const int lr = lane & 15, lg = lane >> 4;
  const bool wactive = (mt * BM + wr * 64) < Ne;

  f32x4 acc[4][4];
#pragma unroll
  for (int m = 0; m < 4; m++)
#pragma unroll
    for (int n = 0; n < 4; n++) acc[m][n] = (f32x4){0.f, 0.f, 0.f, 0.f};

  for (int ks = 0; ks < KD / BK; ++ks) {
    const int k0 = ks * BK;
    __syncthreads();
    // stage A
#pragma unroll
    for (int i = 0; i < 4; i++) {
      ushort4 hh;
      if constexpr (FC1) {
        float4 v = *reinterpret_cast<const float4*>(aptrf[i] + k0);
        hh.x = f2bf(v.x); hh.y = f2bf(v.y); hh.z = f2bf(v.z); hh.w = f2bf(v.w);
      } else {
        hh = *reinterpret_cast<const ushort4*>(aptrh[i] + k0);
      }
      *reinterpret_cast<ushort4*>(&As[arow[i]][akq[i] * 4]) = hh;
    }
    // stage B (transposed into LDS: Bs[n][k]); coalesced scalar loads along n
#pragma unroll
    for (int i = 0; i < 2; i++) {
      const float* bp = W + (size_t)(k0 + bkq_[i] * 4) * ND + bn_[i];
      ushort4 hh;
      hh.x = f2bf(bp[0]);
      hh.y = f2bf(bp[(size_t)ND]);
      hh.z = f2bf(bp[2 * (size_t)ND]);
      hh.w = f2bf(bp[3 * (size_t)ND]);
      *reinterpret_cast<ushort4*>(&Bs[bn_[i]][bkq_[i] * 4]) = hh;
    }
    __syncthreads();
    if (wactive) {
      short8 af[4], bfv[4];
#pragma unroll
      for (int m = 0; m < 4; m++) {
        const unsigned short* p = &As[wr * 64 + m * 16 + lr][lg * 8];
        union { short8 v; ushort4 q[2]; } u;
        u.q[0] = *reinterpret_cast<const ushort4*>(p);
        u.q[1] = *reinterpret_cast<const ushort4*>(p + 4);
        af[m] = u.v;
      }
#pragma unroll
      for (int n = 0; n < 4; n++) {
        const unsigned short* p = &Bs[wc * 64 + n * 16 + lr][lg * 8];
        union { short8 v; ushort4 q[2]; } u;
        u.q[0] = *reinterpret_cast<const ushort4*>(p);
        u.q[1] = *reinterpret_cast<const ushort4*>(p + 4);
        bfv[n] = u.v;
      }
#pragma unroll
      for (int m = 0; m < 4; m++)
#pragma unroll
        for (int n = 0; n < 4; n++)
          acc[m][n] = __builtin_amdgcn_mfma_f32_16x16x32_bf16(af[m], bfv[n], acc[m][n], 0, 0, 0);
    }
  }
  if (!wactive) return;
  // epilogue: C/D layout col = lane&15, row = (lane>>4)*4 + reg  (m89-verified)
#pragma unroll
  for (int n = 0; n < 4; n++) {
    const int col = nt * BN + wc * 64 + n * 16 + lr;
    const float bias = bg[(size_t)e * ND + col];
#pragma unroll
    for (int m = 0; m < 4; m++) {
      const int rbase = mt * BM + wr * 64 + m * 16 + lg * 4;
#pragma unroll
      for (int v = 0; v < 4; v++) {
        const int r = rbase + v;
        if (r < Ne) {
          float val = acc[m][n][v] + bias;
          if constexpr (FC1) {
            val = 0.5f * val * (1.0f + erff(val * 0.70710678118654752440f));  // exact GELU
            hout[(size_t)(base + r) * HID + col] = f2bf(val);
          } else {
            obuf[(size_t)(base + r) * DIM + col] = val * rows_w[base + r];
          }
        }
      }
    }
  }
}

// ---------------- combine: y = x + o[slot0] + o[slot1] ----------------
__global__ __launch_bounds__(256) void combine_k(const float* __restrict__ x,
    const float* __restrict__ obuf, const int* __restrict__ slot_of,
    float* __restrict__ out)
{
  const int t = blockIdx.x, c = threadIdx.x;   // 256 threads x float4 = 1024 floats
  const int s0 = slot_of[2*t], s1 = slot_of[2*t+1];
  const float4 a = reinterpret_cast<const float4*>(x + (size_t)t * DIM)[c];
  const float4 b = reinterpret_cast<const float4*>(obuf + (size_t)s0 * DIM)[c];
  const float4 d = reinterpret_cast<const float4*>(obuf + (size_t)s1 * DIM)[c];
  float4 r;
  r.x = a.x + b.x + d.x; r.y = a.y + b.y + d.y;
  r.z = a.z + b.z + d.z; r.w = a.w + b.w + d.w;
  reinterpret_cast<float4*>(out + (size_t)t * DIM)[c] = r;
}

extern "C" void kernel_launch(void* const* d_in, const int* in_sizes, int n_in,
                              void* d_out, int out_size, void* d_ws, size_t ws_size,
                              hipStream_t stream) {
  const float* x  = (const float*)d_in[0];
  const float* Wr = (const float*)d_in[1];
  const float* br = (const float*)d_in[2];
  const float* W1 = (const float*)d_in[3];
  const float* b1 = (const float*)d_in[4];
  const float* W2 = (const float*)d_in[5];
  const float* b2 = (const float*)d_in[6];
  float* out = (float*)d_out;
  char* ws = (char*)d_ws;

  int*   cnt        = (int*)  (ws + 0);
  int*   basev      = (int*)  (ws + 64);
  int*   fill       = (int*)  (ws + 128);
  int*   re         = (int*)  (ws + 256);
  float* rwv        = (float*)(ws + 256 + 16384);
  int*   rows_token = (int*)  (ws + 256 + 2 * 16384);
  float* rows_w     = (float*)(ws + 256 + 3 * 16384);
  int*   slot_of    = (int*)  (ws + 256 + 4 * 16384);
  unsigned short* hbuf = (unsigned short*)(ws + (1 << 17));                       // 4096 x 2048 bf16 = 16 MB
  float* obuf          = (float*)(ws + (1 << 17) + (size_t)4096 * 2048 * 2);      // 4096 x 1024 f32  = 16 MB

  init_k<<<dim3(1), dim3(64), 0, stream>>>(cnt, fill);
  router_k<<<dim3(T_TOK / 4), dim3(256), 0, stream>>>(x, Wr, br, re, rwv, cnt);
  scan_k<<<dim3(1), dim3(64), 0, stream>>>(cnt, basev);
  scatter_k<<<dim3(T_TOK / 256), dim3(256), 0, stream>>>(re, rwv, basev, fill,
                                                         rows_token, rows_w, slot_of);
  expert_gemm_k<true><<<dim3(HID / 128, T_TOK / 256, NEXP), dim3(512), 0, stream>>>(
      x, hbuf, W1, b1, cnt, basev, rows_token, rows_w, hbuf, obuf);
  expert_gemm_k<false><<<dim3(DIM / 128, T_TOK / 256, NEXP), dim3(512), 0, stream>>>(
      x, hbuf, W2, b2, cnt, basev, rows_token, rows_w, hbuf, obuf);
  combine_k<<<dim3(T_TOK), dim3(256), 0, stream>>>(x, obuf, slot_of, out);
}

// Round 3
// 270.798 us; speedup vs baseline: 1.3364x; 1.3364x over previous
//
#include <hip/hip_runtime.h>
#include <hip/hip_bf16.h>

#define T_TOK 2048
#define DIM   1024
#define NEXP  16
#define HID   2048

typedef __attribute__((ext_vector_type(8))) short short8;
typedef __attribute__((ext_vector_type(4))) float f32x4;

__device__ __forceinline__ unsigned short f2bf(float f) {
  __hip_bfloat16 h = __float2bfloat16(f);
  union { __hip_bfloat16 b; unsigned short u; } cv; cv.b = h; return cv.u;
}

// ---------------- init: zero counters ----------------
__global__ void init_k(int* cnt, int* fill) {
  int i = threadIdx.x;
  if (i < NEXP) { cnt[i] = 0; fill[i] = 0; }
}

// ---------------- router: fp32, one wave per token ----------------
__global__ __launch_bounds__(256) void router_k(const float* __restrict__ x,
    const float* __restrict__ Wr, const float* __restrict__ br,
    int* __restrict__ re, float* __restrict__ rwv, int* __restrict__ cnt)
{
  const int wid = threadIdx.x >> 6, lane = threadIdx.x & 63;
  const int t = blockIdx.x * 4 + wid;
  const float* xr = x + (size_t)t * DIM;
  float acc[NEXP];
#pragma unroll
  for (int e = 0; e < NEXP; e++) acc[e] = 0.f;
  for (int i = 0; i < DIM / 64; i++) {
    const int d = lane + 64 * i;
    const float xv = xr[d];
    const float4* w4 = reinterpret_cast<const float4*>(Wr + (size_t)d * NEXP);
#pragma unroll
    for (int q = 0; q < 4; q++) {
      float4 w = w4[q];
      acc[4*q+0] += xv * w.x; acc[4*q+1] += xv * w.y;
      acc[4*q+2] += xv * w.z; acc[4*q+3] += xv * w.w;
    }
  }
#pragma unroll
  for (int e = 0; e < NEXP; e++) {
    float v = acc[e];
    v += __shfl_xor(v, 32); v += __shfl_xor(v, 16); v += __shfl_xor(v, 8);
    v += __shfl_xor(v, 4);  v += __shfl_xor(v, 2);  v += __shfl_xor(v, 1);
    acc[e] = v;
  }
  if (lane == 0) {
    float lg[NEXP];
#pragma unroll
    for (int e = 0; e < NEXP; e++) lg[e] = acc[e] + br[e];  // TEMP = 1.0
    int e0 = 0; float b0 = lg[0];
    for (int e = 1; e < NEXP; e++) if (lg[e] > b0) { b0 = lg[e]; e0 = e; }
    int e1 = (e0 == 0) ? 1 : 0; float b1v = lg[e1];
    for (int e = 0; e < NEXP; e++) if (e != e0 && lg[e] > b1v) { b1v = lg[e]; e1 = e; }
    float p1 = expf(b1v - b0);               // p0 = 1
    float inv = 1.0f / (1.0f + p1);
    re[2*t] = e0; re[2*t+1] = e1;
    rwv[2*t] = inv; rwv[2*t+1] = p1 * inv;
    atomicAdd(&cnt[e0], 1); atomicAdd(&cnt[e1], 1);
  }
}

// ---------------- scan: prefix + flat m-tile list ----------------
__global__ void scan_k(const int* cnt, int* basev, int* tile_e, int* tile_m0, int* ntt) {
  if (threadIdx.x == 0) {
    int s = 0, t = 0;
    for (int e = 0; e < NEXP; e++) {
      basev[e] = s;
      for (int m0 = 0; m0 < cnt[e]; m0 += 256) { tile_e[t] = e; tile_m0[t] = m0; t++; }
      s += cnt[e];
    }
    ntt[0] = t;
  }
}

// ---------------- scatter: build per-expert row lists ----------------
__global__ __launch_bounds__(256) void scatter_k(const int* __restrict__ re,
    const float* __restrict__ rwv, const int* __restrict__ basev, int* fill,
    int* __restrict__ rows_token, float* __restrict__ rows_w, int* __restrict__ slot_of)
{
  int t = blockIdx.x * 256 + threadIdx.x;
  if (t >= T_TOK) return;
  for (int k = 0; k < 2; k++) {
    int e = re[2*t+k];
    int pos = atomicAdd(&fill[e], 1);
    int row = basev[e] + pos;
    rows_token[row] = t;
    rows_w[row] = rwv[2*t+k];
    slot_of[2*t+k] = row;
  }
}

// ---------------- gather: xg[row] = bf16(x[token]) ----------------
__global__ __launch_bounds__(256) void gather_k(const float* __restrict__ x,
    const int* __restrict__ rows_token, unsigned short* __restrict__ xg)
{
  const int row = blockIdx.x, t = threadIdx.x;
  const int tok = rows_token[row];
  float4 v = reinterpret_cast<const float4*>(x + (size_t)tok * DIM)[t];
  ushort4 h;
  h.x = f2bf(v.x); h.y = f2bf(v.y); h.z = f2bf(v.z); h.w = f2bf(v.w);
  reinterpret_cast<ushort4*>(xg + (size_t)row * DIM)[t] = h;
}

// ---------------- grouped expert GEMM (fc1 / fc2) ----------------
// A (bf16, compact rows): fc1 = xg [4096][1024], fc2 = hbuf [4096][2048]
// B (fp32 weights [K][N]): fc1 = W1[e], fc2 = W2[e]
// out: fc1 -> GELU -> hbuf (bf16); fc2 -> (acc+b2)*w -> obuf (f32)
template<bool FC1>
__global__ __launch_bounds__(256) void expert_gemm_k(
    const unsigned short* __restrict__ Ag,
    const float* __restrict__ Wg, const float* __restrict__ bg,
    const int* __restrict__ cnt, const int* __restrict__ basev,
    const int* __restrict__ tile_e, const int* __restrict__ tile_m0,
    const int* __restrict__ ntt, const float* __restrict__ rows_w,
    unsigned short* __restrict__ hout, float* __restrict__ obuf)
{
  constexpr int KD = FC1 ? DIM : HID;
  constexpr int ND = FC1 ? HID : DIM;
  constexpr int BM = 256, BN = 64, BK = 32, LDP = 36;
  constexpr int NK = KD / BK;
  if ((int)blockIdx.y >= ntt[0]) return;
  const int e  = tile_e[blockIdx.y], m0 = tile_m0[blockIdx.y];
  const int Ne = cnt[e], base = basev[e];
  const int nt = blockIdx.x;
  __shared__ unsigned short As[BM][LDP];
  __shared__ unsigned short Bs[BN][LDP];
  const int tid = threadIdx.x;
  const float* W = Wg + (size_t)e * KD * ND + nt * BN;

  // A staging: 256 rows x 4 kq (8 bf16 each) = 1024 slots / 256 thr = 4 each
  const unsigned short* aptr[4];
  int arow[4], akq[4];
#pragma unroll
  for (int i = 0; i < 4; i++) {
    int flat = tid + 256 * i;
    int row = flat >> 2, kq = flat & 3;
    arow[i] = row; akq[i] = kq;
    int g = m0 + row; if (g >= Ne) g = Ne - 1;
    aptr[i] = Ag + (size_t)(base + g) * KD + kq * 8;
  }
  // B staging: 64 n x 8 kq (4 fp32 cols each) = 512 slots / 256 thr = 2 each
  int bn_[2], bkq[2];
  const float* bptr[2];
#pragma unroll
  for (int i = 0; i < 2; i++) {
    int flat = tid + 256 * i;
    bn_[i] = flat & 63; bkq[i] = flat >> 6;
    bptr[i] = W + (size_t)(bkq[i] * 4) * ND + bn_[i];
  }

  const int wid = tid >> 6, lane = tid & 63;
  const int lr = lane & 15, lg = lane >> 4;
  const bool wactive = (m0 + wid * 64) < Ne;   // waves stacked 4-deep in m

  f32x4 acc[4][4];
#pragma unroll
  for (int m = 0; m < 4; m++)
#pragma unroll
    for (int n = 0; n < 4; n++) acc[m][n] = (f32x4){0.f, 0.f, 0.f, 0.f};

  // prologue: load k-step 0 into registers
  ushort4 va[4][2];
  float   vb[2][4];
#pragma unroll
  for (int i = 0; i < 4; i++) {
    va[i][0] = *reinterpret_cast<const ushort4*>(aptr[i]);
    va[i][1] = *reinterpret_cast<const ushort4*>(aptr[i] + 4);
  }
#pragma unroll
  for (int i = 0; i < 2; i++) {
    const float* p = bptr[i];
    vb[i][0] = p[0]; vb[i][1] = p[(size_t)ND];
    vb[i][2] = p[2 * (size_t)ND]; vb[i][3] = p[3 * (size_t)ND];
  }

  for (int ks = 0; ks < NK; ++ks) {
    __syncthreads();                       // LDS free (consumers of ks-1 done)
    // write staged registers to LDS
#pragma unroll
    for (int i = 0; i < 4; i++) {
      unsigned short* d = &As[arow[i]][akq[i] * 8];
      *reinterpret_cast<ushort4*>(d)     = va[i][0];
      *reinterpret_cast<ushort4*>(d + 4) = va[i][1];
    }
#pragma unroll
    for (int i = 0; i < 2; i++) {
      ushort4 h;
      h.x = f2bf(vb[i][0]); h.y = f2bf(vb[i][1]);
      h.z = f2bf(vb[i][2]); h.w = f2bf(vb[i][3]);
      *reinterpret_cast<ushort4*>(&Bs[bn_[i]][bkq[i] * 4]) = h;
    }
    __syncthreads();
    // issue next k-step's global loads now; latency hides under frag+MFMA
    if (ks + 1 < NK) {
      const int k0 = (ks + 1) * BK;
#pragma unroll
      for (int i = 0; i < 4; i++) {
        va[i][0] = *reinterpret_cast<const ushort4*>(aptr[i] + k0);
        va[i][1] = *reinterpret_cast<const ushort4*>(aptr[i] + k0 + 4);
      }
#pragma unroll
      for (int i = 0; i < 2; i++) {
        const float* p = bptr[i] + (size_t)k0 * ND;
        vb[i][0] = p[0]; vb[i][1] = p[(size_t)ND];
        vb[i][2] = p[2 * (size_t)ND]; vb[i][3] = p[3 * (size_t)ND];
      }
    }
    if (wactive) {
      short8 af[4], bfv[4];
#pragma unroll
      for (int m = 0; m < 4; m++) {
        const unsigned short* p = &As[wid * 64 + m * 16 + lr][lg * 8];
        union { short8 v; ushort4 q[2]; } u;
        u.q[0] = *reinterpret_cast<const ushort4*>(p);
        u.q[1] = *reinterpret_cast<const ushort4*>(p + 4);
        af[m] = u.v;
      }
#pragma unroll
      for (int n = 0; n < 4; n++) {
        const unsigned short* p = &Bs[n * 16 + lr][lg * 8];
        union { short8 v; ushort4 q[2]; } u;
        u.q[0] = *reinterpret_cast<const ushort4*>(p);
        u.q[1] = *reinterpret_cast<const ushort4*>(p + 4);
        bfv[n] = u.v;
      }
#pragma unroll
      for (int m = 0; m < 4; m++)
#pragma unroll
        for (int n = 0; n < 4; n++)
          acc[m][n] = __builtin_amdgcn_mfma_f32_16x16x32_bf16(af[m], bfv[n], acc[m][n], 0, 0, 0);
    }
  }
  if (!wactive) return;
  // epilogue: C/D layout col = lane&15, row = (lane>>4)*4 + reg (m89-verified)
#pragma unroll
  for (int n = 0; n < 4; n++) {
    const int col = nt * BN + n * 16 + lr;
    const float bias = bg[(size_t)e * ND + col];
#pragma unroll
    for (int m = 0; m < 4; m++) {
      const int rbase = m0 + wid * 64 + m * 16 + lg * 4;
#pragma unroll
      for (int v = 0; v < 4; v++) {
        const int r = rbase + v;
        if (r < Ne) {
          float val = acc[m][n][v] + bias;
          if constexpr (FC1) {
            val = 0.5f * val * (1.0f + erff(val * 0.70710678118654752440f));  // exact GELU
            hout[(size_t)(base + r) * HID + col] = f2bf(val);
          } else {
            obuf[(size_t)(base + r) * DIM + col] = val * rows_w[base + r];
          }
        }
      }
    }
  }
}

// ---------------- combine: y = x + o[slot0] + o[slot1] ----------------
__global__ __launch_bounds__(256) void combine_k(const float* __restrict__ x,
    const float* __restrict__ obuf, const int* __restrict__ slot_of,
    float* __restrict__ out)
{
  const int t = blockIdx.x, c = threadIdx.x;
  const int s0 = slot_of[2*t], s1 = slot_of[2*t+1];
  const float4 a = reinterpret_cast<const float4*>(x + (size_t)t * DIM)[c];
  const float4 b = reinterpret_cast<const float4*>(obuf + (size_t)s0 * DIM)[c];
  const float4 d = reinterpret_cast<const float4*>(obuf + (size_t)s1 * DIM)[c];
  float4 r;
  r.x = a.x + b.x + d.x; r.y = a.y + b.y + d.y;
  r.z = a.z + b.z + d.z; r.w = a.w + b.w + d.w;
  reinterpret_cast<float4*>(out + (size_t)t * DIM)[c] = r;
}

extern "C" void kernel_launch(void* const* d_in, const int* in_sizes, int n_in,
                              void* d_out, int out_size, void* d_ws, size_t ws_size,
                              hipStream_t stream) {
  const float* x  = (const float*)d_in[0];
  const float* Wr = (const float*)d_in[1];
  const float* br = (const float*)d_in[2];
  const float* W1 = (const float*)d_in[3];
  const float* b1 = (const float*)d_in[4];
  const float* W2 = (const float*)d_in[5];
  const float* b2 = (const float*)d_in[6];
  float* out = (float*)d_out;
  char* ws = (char*)d_ws;

  int*   cnt        = (int*)  (ws + 0);
  int*   basev      = (int*)  (ws + 64);
  int*   fill       = (int*)  (ws + 128);
  int*   ntt        = (int*)  (ws + 192);
  int*   tile_e     = (int*)  (ws + 256);
  int*   tile_m0    = (int*)  (ws + 512);
  int*   re         = (int*)  (ws + 4096);
  float* rwv        = (float*)(ws + 4096 + 16384);
  int*   rows_token = (int*)  (ws + 4096 + 2 * 16384);
  float* rows_w     = (float*)(ws + 4096 + 3 * 16384);
  int*   slot_of    = (int*)  (ws + 4096 + 4 * 16384);
  unsigned short* xg   = (unsigned short*)(ws + ((size_t)(1 << 17)));                      // 4096x1024 bf16 = 8 MB
  unsigned short* hbuf = (unsigned short*)(ws + ((size_t)(1 << 17) + ((size_t)8 << 20)));  // 4096x2048 bf16 = 16 MB
  float* obuf          = (float*)         (ws + ((size_t)(1 << 17) + ((size_t)24 << 20))); // 4096x1024 f32  = 16 MB

  init_k<<<dim3(1), dim3(64), 0, stream>>>(cnt, fill);
  router_k<<<dim3(T_TOK / 4), dim3(256), 0, stream>>>(x, Wr, br, re, rwv, cnt);
  scan_k<<<dim3(1), dim3(64), 0, stream>>>(cnt, basev, tile_e, tile_m0, ntt);
  scatter_k<<<dim3(T_TOK / 256), dim3(256), 0, stream>>>(re, rwv, basev, fill,
                                                         rows_token, rows_w, slot_of);
  gather_k<<<dim3(2 * T_TOK), dim3(256), 0, stream>>>(x, rows_token, xg);
  expert_gemm_k<true><<<dim3(HID / 64, 32), dim3(256), 0, stream>>>(
      xg, W1, b1, cnt, basev, tile_e, tile_m0, ntt, rows_w, hbuf, obuf);
  expert_gemm_k<false><<<dim3(DIM / 64, 32), dim3(256), 0, stream>>>(
      hbuf, W2, b2, cnt, basev, tile_e, tile_m0, ntt, rows_w, hbuf, obuf);
  combine_k<<<dim3(T_TOK), dim3(256), 0, stream>>>(x, obuf, slot_of, out);
}